// Round 6
// baseline (150.682 us; speedup 1.0000x reference)
//
#include <hip/hip_runtime.h>

#define N_NODES  100000
#define N_EDGES  1600000
#define D        128
#define NG       64
#define NC       10
#define NBMAX    512      // gemm grid: 2 blocks/CU (1024 thr each)
#define TILE     64       // nodes per LDS tile
#define EBLK     1563     // edge blocks in fused edge+count kernel (1.6M/4/256)
#define CBLK     391      // node-count blocks (ceil(100000/256))

typedef unsigned int uint;
typedef unsigned long long ull;

static_assert(N_EDGES % 4 == 0, "int4 edge loads");
static_assert(EBLK * 256 * 4 >= N_EDGES, "edge coverage");

// ---------------------------------------------------------------------------
// Kernel 0: zero cnt (u8-packed counts) + counts[64] (contiguous region).
// ---------------------------------------------------------------------------
__global__ __launch_bounds__(256) void zero_kernel(uint4* __restrict__ p, int n4)
{
    int i = blockIdx.x * 256 + threadIdx.x;
    const int stride = gridDim.x * 256;
    const uint4 z = {0u, 0u, 0u, 0u};
    for (; i < n4; i += stride) p[i] = z;
}

// ---------------------------------------------------------------------------
// Kernel 1 (fused): blocks [0,EBLK) build cnt[n][g] (4 graphs packed per u32,
// fire-and-forget int atomics -> fabric-atomic-rate bound, ~68us floor);
// blocks [EBLK, EBLK+CBLK) compute per-graph node counts via sorted-run
// detection (few atomics). The two roles touch disjoint outputs.
// ---------------------------------------------------------------------------
__global__ __launch_bounds__(256) void edge_count_kernel(
    const int* __restrict__ ei, const int* __restrict__ batch,
    uint* __restrict__ cnt, int* __restrict__ counts)
{
    const int b = blockIdx.x;
    if (b < EBLK) {
        const int e0 = (b * 256 + threadIdx.x) * 4;
        if (e0 >= N_EDGES) return;
        const int4 s4 = *reinterpret_cast<const int4*>(ei + e0);
        const int4 d4 = *reinterpret_cast<const int4*>(ei + N_EDGES + e0);
        const int g0 = batch[d4.x], g1 = batch[d4.y];
        const int g2 = batch[d4.z], g3 = batch[d4.w];
        atomicAdd(&cnt[(size_t)s4.x * 16 + (g0 >> 2)], 1u << ((g0 & 3) * 8));
        atomicAdd(&cnt[(size_t)s4.y * 16 + (g1 >> 2)], 1u << ((g1 & 3) * 8));
        atomicAdd(&cnt[(size_t)s4.z * 16 + (g2 >> 2)], 1u << ((g2 & 3) * 8));
        atomicAdd(&cnt[(size_t)s4.w * 16 + (g3 >> 2)], 1u << ((g3 & 3) * 8));
    } else {
        const int n = (b - EBLK) * 256 + threadIdx.x;
        if (n >= N_NODES) return;
        const int lane = threadIdx.x & 63;
        const int g = batch[n];
        const bool lead = (n == 0) || (lane == 0) || (batch[n - 1] != g);
        const ull bl = __ballot(lead);
        if (lead) {
            const ull higher = (lane == 63) ? 0ull : (bl >> (lane + 1));
            int end = higher ? (lane + 1 + (__ffsll(higher) - 1)) : 64;
            const int wb = n - lane;
            int nv = N_NODES - wb; if (nv > 64) nv = 64;
            if (end > nv) end = nv;
            atomicAdd(&counts[g], end - lane);
        }
    }
}

// ---------------------------------------------------------------------------
// Kernel 3: dense GEMM  agg[g][d] = sum_n cnt[n][g]*x[n][d]  (+ self-sums via
// sorted run-sum). 1024 threads = 16 waves; wave q owns graphs 4q..4q+3;
// thread (q, d2=t&63) owns dims {2*d2, 2*d2+1}. float2 accumulators to let
// the backend form v_pk_fma_f32. batch sorted => ~96% of 64-node tiles are
// graph-uniform: branch-free fast path, per-node run-check only on boundary
// tiles. 2 blocks/CU (49.9 KB LDS). No atomics.
// ---------------------------------------------------------------------------
__device__ __forceinline__ void pk_fma(float2& a, float s, float2 v)
{
    a.x = fmaf(s, v.x, a.x);
    a.y = fmaf(s, v.y, a.y);
}

#define FLUSH_X()                                                       \
    if ((cur_g >> 2) == q) {                                            \
        switch (cur_g & 3) {                                            \
            case 0: xA.x += rs.x; xA.y += rs.y; break;                  \
            case 1: xB.x += rs.x; xB.y += rs.y; break;                  \
            case 2: xC.x += rs.x; xC.y += rs.y; break;                  \
            case 3: xD.x += rs.x; xD.y += rs.y; break;                  \
        }                                                               \
    }

__global__ __launch_bounds__(1024) void gemm_kernel(
    const float* __restrict__ x, const uint* __restrict__ cnt,
    const int* __restrict__ batch,
    float* __restrict__ partA, float* __restrict__ partX, int NBe)
{
    __shared__ float xs[TILE * D];       // [n][d], 32 KB
    __shared__ float cs[TILE * 68];      // [n][g] padded rows (16B-aligned)
    __shared__ int   bs[TILE];

    const int t  = threadIdx.x;
    const int d2 = t & 63;
    const int q  = t >> 6;               // wave-uniform, 0..15

    float2 aA = {0,0}, aB = {0,0}, aC = {0,0}, aD = {0,0};
    float2 xA = {0,0}, xB = {0,0}, xC = {0,0}, xD = {0,0};
    float2 rs = {0,0};
    int cur_g = -1;

    const int ntiles = (N_NODES + TILE - 1) / TILE;
    for (int tb = blockIdx.x; tb < ntiles; tb += NBe) {
        const int base = tb * TILE;
        const int nvalid = min(TILE, N_NODES - base);

        // stage x: 2 float4 per thread, coalesced global, consecutive LDS b128
        #pragma unroll
        for (int k = 0; k < 2; ++k) {
            const int f4 = t + k * 1024;
            const int n  = f4 >> 5;
            const int c4 = f4 & 31;
            float4 v = make_float4(0.f, 0.f, 0.f, 0.f);
            if (n < nvalid)
                v = *reinterpret_cast<const float4*>(x + (size_t)(base + n) * D + c4 * 4);
            reinterpret_cast<float4*>(xs)[f4] = v;
        }
        // stage cnt: 1 u32 per thread -> 4 floats
        {
            const int node = t >> 4, slot = t & 15;
            uint cv = 0u;
            if (node < nvalid) cv = cnt[(size_t)(base + node) * 16 + slot];
            float* cb = cs + node * 68 + slot * 4;
            cb[0] = (float)(cv & 255u);
            cb[1] = (float)((cv >> 8) & 255u);
            cb[2] = (float)((cv >> 16) & 255u);
            cb[3] = (float)(cv >> 24);
        }
        if (t < TILE) bs[t] = (t < nvalid) ? batch[base + t] : -1;
        __syncthreads();

        const float2* __restrict__ xv = reinterpret_cast<const float2*>(xs) + d2;
        const float*  __restrict__ cv = cs + q * 4;

        if (bs[0] == bs[TILE - 1]) {
            // uniform tile (common: batch sorted, <=63 boundaries overall)
            const int bg = bs[0];
            if (bg != cur_g) {
                FLUSH_X();
                rs.x = 0.f; rs.y = 0.f;
                cur_g = bg;
            }
            #pragma unroll 4
            for (int n = 0; n < TILE; ++n) {
                const float2 v = xv[n * 64];
                const float4 c = *reinterpret_cast<const float4*>(cv + n * 68);
                rs.x += v.x; rs.y += v.y;
                pk_fma(aA, c.x, v);
                pk_fma(aB, c.y, v);
                pk_fma(aC, c.z, v);
                pk_fma(aD, c.w, v);
            }
        } else {
            // boundary tile: per-node run detection
            #pragma unroll 4
            for (int n = 0; n < TILE; ++n) {
                const float2 v = xv[n * 64];
                const float4 c = *reinterpret_cast<const float4*>(cv + n * 68);
                const int bg = bs[n];
                if (bg != cur_g) {                   // wave-uniform branch
                    FLUSH_X();
                    rs.x = 0.f; rs.y = 0.f;
                    cur_g = bg;
                }
                rs.x += v.x; rs.y += v.y;
                pk_fma(aA, c.x, v);
                pk_fma(aB, c.y, v);
                pk_fma(aC, c.z, v);
                pk_fma(aD, c.w, v);
            }
        }
        __syncthreads();
    }
    FLUSH_X();                                       // final run flush

    float* pa = partA + (size_t)blockIdx.x * (NG * D);
    float* px = partX + (size_t)blockIdx.x * (NG * D);
    const int gb = q * 4;
    reinterpret_cast<float2*>(pa + (size_t)(gb + 0) * D)[d2] = aA;
    reinterpret_cast<float2*>(pa + (size_t)(gb + 1) * D)[d2] = aB;
    reinterpret_cast<float2*>(pa + (size_t)(gb + 2) * D)[d2] = aC;
    reinterpret_cast<float2*>(pa + (size_t)(gb + 3) * D)[d2] = aD;
    reinterpret_cast<float2*>(px + (size_t)(gb + 0) * D)[d2] = xA;
    reinterpret_cast<float2*>(px + (size_t)(gb + 1) * D)[d2] = xB;
    reinterpret_cast<float2*>(px + (size_t)(gb + 2) * D)[d2] = xC;
    reinterpret_cast<float2*>(px + (size_t)(gb + 3) * D)[d2] = xD;
}

// ---------------------------------------------------------------------------
// Kernel 4: partial reduction, fully coalesced. 256 blocks: column-block
// (cb=b&63 -> 256 columns of the 16384-wide [A|X] space) x partial-chunk
// (pc=b>>6 of 4). Writes tmp2[pc][16384].
// ---------------------------------------------------------------------------
__global__ __launch_bounds__(256) void reduce1_kernel(
    const float* __restrict__ partA, const float* __restrict__ partX,
    float* __restrict__ tmp2, int NBe)
{
    const int cb = blockIdx.x & 63;
    const int pc = blockIdx.x >> 6;
    const int c  = cb * 256 + threadIdx.x;       // 0..16383
    const float* __restrict__ srcp =
        (c < NG * D) ? (partA + c) : (partX + (c - NG * D));
    const int chunk = (NBe + 3) >> 2;
    const int p0 = pc * chunk;
    int p1 = p0 + chunk; if (p1 > NBe) p1 = NBe;
    float s = 0.f;
    #pragma unroll 8
    for (int p = p0; p < p1; ++p) s += srcp[(size_t)p * (NG * D)];
    tmp2[pc * (2 * NG * D) + c] = s;
}

// ---------------------------------------------------------------------------
// Kernel 5: final 4-way sum + matvec pair + classifier. Block = graph.
// ---------------------------------------------------------------------------
__global__ __launch_bounds__(128) void final_kernel(
    const float* __restrict__ tmp2, const int* __restrict__ counts,
    const float* __restrict__ w_rel, const float* __restrict__ b_rel,
    const float* __restrict__ w_root,
    const float* __restrict__ w_lin, const float* __restrict__ b_lin,
    float* __restrict__ out)
{
    const int g = blockIdx.x;
    const int t = threadIdx.x;   // 0..127

    __shared__ float agg_s[D], x_s[D], p_s[D];
    float a = 0.f, xsum = 0.f;
    #pragma unroll
    for (int j = 0; j < 4; ++j) {
        a    += tmp2[j * (2 * NG * D) + g * D + t];
        xsum += tmp2[j * (2 * NG * D) + NG * D + g * D + t];
    }
    agg_s[t] = a; x_s[t] = xsum;
    __syncthreads();

    const float cn = (float)counts[g];
    float hj = b_rel[t] * cn;
    const float* __restrict__ wr = w_rel  + (size_t)t * D;
    const float* __restrict__ wo = w_root + (size_t)t * D;
    #pragma unroll 8
    for (int d0 = 0; d0 < D; ++d0) hj += agg_s[d0] * wr[d0] + x_s[d0] * wo[d0];
    p_s[t] = hj / fmaxf(cn, 1.f);
    __syncthreads();

    if (t < NC) {
        const float* __restrict__ wl = w_lin + (size_t)t * D;
        float o = b_lin[t];
        #pragma unroll 8
        for (int d0 = 0; d0 < D; ++d0) o += p_s[d0] * wl[d0];
        out[g * NC + t] = o;
    }
}

extern "C" void kernel_launch(void* const* d_in, const int* in_sizes, int n_in,
                              void* d_out, int out_size, void* d_ws, size_t ws_size,
                              hipStream_t stream)
{
    const float* x      = (const float*)d_in[0];
    const int*   ei     = (const int*)  d_in[1];
    const int*   batch  = (const int*)  d_in[2];
    const float* w_rel  = (const float*)d_in[3];
    const float* b_rel  = (const float*)d_in[4];
    const float* w_root = (const float*)d_in[5];
    const float* w_lin  = (const float*)d_in[6];
    const float* b_lin  = (const float*)d_in[7];
    float* out = (float*)d_out;

    // ws layout: cnt (6.4 MB) | counts (64 int) | tmp2 (256 KB) | partA | partX
    const size_t cntf  = (size_t)N_NODES * 16;       // u32 units
    const size_t tmp2f = 4 * (size_t)(2 * NG * D);
    uint*  cnt    = (uint*)d_ws;
    int*   counts = (int*)(cnt + cntf);
    float* tmp2   = (float*)(counts + 64);
    float* partA  = tmp2 + tmp2f;

    const size_t availf = ws_size / sizeof(float);
    const size_t headf  = cntf + 64 + tmp2f;
    int NBe = NBMAX;
    if (headf + (size_t)NBe * 2 * NG * D > availf) {
        long long rem = (long long)availf - (long long)headf;
        long long nb  = rem / (2 * NG * D);
        NBe = (nb < 1) ? 1 : (int)nb;
    }
    float* partX = partA + (size_t)NBe * NG * D;

    const int zero_n4 = (int)((cntf * 4 + 256) / 16);
    zero_kernel<<<1024, 256, 0, stream>>>((uint4*)d_ws, zero_n4);
    edge_count_kernel<<<EBLK + CBLK, 256, 0, stream>>>(ei, batch, cnt, counts);
    gemm_kernel<<<NBe, 1024, 0, stream>>>(x, cnt, batch, partA, partX, NBe);
    reduce1_kernel<<<256, 256, 0, stream>>>(partA, partX, tmp2, NBe);
    final_kernel<<<NG, 128, 0, stream>>>(tmp2, counts,
                                         w_rel, b_rel, w_root, w_lin, b_lin, out);
}

// Round 7
// 113.787 us; speedup vs baseline: 1.3243x; 1.3243x over previous
//
#include <hip/hip_runtime.h>

#define N_NODES  100000
#define N_EDGES  1600000
#define D        128
#define NG       64
#define NC       10
#define NBMAX    512      // gemm grid: 2 blocks/CU (1024 thr each)
#define TILE     64       // nodes per LDS tile
#define EPT      8        // edges per thread in bucket_kernel
#define ABLK     196      // ceil(N_EDGES / (1024*EPT))
#define NBUCK    391      // ceil(N_NODES / 256) src buckets
#define BCAP     8192     // u16 slots per bucket (mean fill ~6650, 64B-aligned runs)
#define CBLK2    98       // ceil(N_NODES / 1024) node-count blocks

typedef unsigned int uint;
typedef unsigned short ushort;
typedef unsigned long long ull;

static_assert(ABLK * 1024 * EPT >= N_EDGES, "edge coverage");
static_assert(NBUCK * 256 >= N_NODES, "bucket coverage");

// ---------------------------------------------------------------------------
// Kernel 0: init ws head: tail[NBUCK]+counts[64]+pad -> 0 (first 512 u32),
// bucketData (NBUCK*BCAP u16) -> 0xFFFF sentinel.
// ---------------------------------------------------------------------------
__global__ __launch_bounds__(256) void fill_kernel(uint* __restrict__ p,
                                                   int n_zero, int n_total)
{
    int i = blockIdx.x * 256 + threadIdx.x;
    const int stride = gridDim.x * 256;
    for (; i < n_total; i += stride) p[i] = (i < n_zero) ? 0u : 0xFFFFFFFFu;
}

// ---------------------------------------------------------------------------
// Kernel 1: edge bucketing (replaces the 73us atomic-storm histogram).
// Blocks [0,ABLK): each handles 8192 edges. LDS-histogram 391 src-buckets,
// reserve 64B-aligned runs with ONE global atomic per touched bucket
// (77K total, vs 1.6M before -> far below the fabric atomic ceiling),
// then scatter u16 records (src&255)<<6|g via LDS int cursors. 64B-aligned
// runs mean no cache line is shared across XCDs (no coherence hazard).
// Blocks [ABLK, ABLK+CBLK2): per-graph node counts via sorted-run detection.
// ---------------------------------------------------------------------------
__global__ __launch_bounds__(1024) void bucket_kernel(
    const int* __restrict__ ei, const int* __restrict__ batch,
    uint* __restrict__ tail, int* __restrict__ counts,
    ushort* __restrict__ bdata)
{
    const int b = blockIdx.x;
    if (b < ABLK) {
        __shared__ uint hs[NBUCK];
        const int t = threadIdx.x;
        for (int i = t; i < NBUCK; i += 1024) hs[i] = 0u;
        __syncthreads();

        const int e0 = b * (1024 * EPT) + t * EPT;
        uint er[EPT];
        int  s[EPT], dn[EPT];
        bool v[EPT];
        if (e0 + EPT <= N_EDGES) {
            const int4 a0 = *reinterpret_cast<const int4*>(ei + e0);
            const int4 a1 = *reinterpret_cast<const int4*>(ei + e0 + 4);
            const int4 b0 = *reinterpret_cast<const int4*>(ei + N_EDGES + e0);
            const int4 b1 = *reinterpret_cast<const int4*>(ei + N_EDGES + e0 + 4);
            s[0]=a0.x; s[1]=a0.y; s[2]=a0.z; s[3]=a0.w;
            s[4]=a1.x; s[5]=a1.y; s[6]=a1.z; s[7]=a1.w;
            dn[0]=b0.x; dn[1]=b0.y; dn[2]=b0.z; dn[3]=b0.w;
            dn[4]=b1.x; dn[5]=b1.y; dn[6]=b1.z; dn[7]=b1.w;
            #pragma unroll
            for (int i = 0; i < EPT; ++i) v[i] = true;
        } else {
            #pragma unroll
            for (int i = 0; i < EPT; ++i) {
                v[i] = (e0 + i) < N_EDGES;
                s[i]  = v[i] ? ei[e0 + i] : 0;
                dn[i] = v[i] ? ei[N_EDGES + e0 + i] : 0;
            }
        }
        #pragma unroll
        for (int i = 0; i < EPT; ++i) {
            if (v[i]) {
                const uint g = (uint)batch[dn[i]];
                const uint k = (uint)s[i] >> 8;
                er[i] = (k << 16) | (((uint)s[i] & 255u) << 6) | g;
                atomicAdd(&hs[k], 1u);
            } else er[i] = 0xFFFFFFFFu;
        }
        __syncthreads();
        if (t < NBUCK) {
            const uint c = hs[t];
            uint r = 0u;
            if (c) r = atomicAdd(&tail[t], (c + 31u) & ~31u);  // 64B-aligned run
            hs[t] = r;
        }
        __syncthreads();
        #pragma unroll
        for (int i = 0; i < EPT; ++i) {
            if (er[i] != 0xFFFFFFFFu) {
                const uint k = er[i] >> 16;
                const uint pos = atomicAdd(&hs[k], 1u);
                if (pos < BCAP)
                    bdata[(size_t)k * BCAP + pos] = (ushort)(er[i] & 0xFFFFu);
            }
        }
    } else {
        const int n = (b - ABLK) * 1024 + threadIdx.x;
        if (n >= N_NODES) return;
        const int lane = threadIdx.x & 63;
        const int g = batch[n];
        const bool lead = (n == 0) || (lane == 0) || (batch[n - 1] != g);
        const ull bl = __ballot(lead);
        if (lead) {
            const ull higher = (lane == 63) ? 0ull : (bl >> (lane + 1));
            int end = higher ? (lane + 1 + (__ffsll(higher) - 1)) : 64;
            const int wb = n - lane;
            int nv = N_NODES - wb; if (nv > 64) nv = 64;
            if (end > nv) end = nv;
            atomicAdd(&counts[g], end - lane);
        }
    }
}

// ---------------------------------------------------------------------------
// Kernel 2: per-bucket histogram -> packed-u8 cnt tile. Block k: read own
// bucket contiguously (coalesced), LDS u32 histogram [256 nodes][64 graphs]
// (native ds_add), write cnt rows non-atomically, coalesced. Writes every
// cnt byte -> no global pre-zero of cnt needed.
// ---------------------------------------------------------------------------
__global__ __launch_bounds__(256) void hist_kernel(
    const uint* __restrict__ tail, const ushort* __restrict__ bdata,
    uint* __restrict__ cnt)
{
    __shared__ uint h2[256 * NG];          // 64 KB
    const int k = blockIdx.x;
    const int t = threadIdx.x;
    for (int i = t; i < 256 * NG; i += 256) h2[i] = 0u;
    __syncthreads();

    uint n = tail[k]; if (n > BCAP) n = BCAP;
    const ushort* __restrict__ bp = bdata + (size_t)k * BCAP;
    for (uint i = t; i < n; i += 256) {
        const uint r = bp[i];
        if (r != 0xFFFFu) atomicAdd(&h2[r], 1u);
    }
    __syncthreads();

    const int node0 = k * 256;
    const int nrows = min(256, N_NODES - node0);
    for (int j = t; j < nrows * 16; j += 256) {
        const int node = j >> 4, g4 = j & 15;
        const uint* hp = &h2[node * NG + g4 * 4];
        const uint w = (hp[0] & 255u) | ((hp[1] & 255u) << 8)
                     | ((hp[2] & 255u) << 16) | ((hp[3] & 255u) << 24);
        cnt[(size_t)(node0 + node) * 16 + g4] = w;
    }
}

// ---------------------------------------------------------------------------
// Kernel 3: dense GEMM  agg[g][d] = sum_n cnt[n][g]*x[n][d]  (+ self-sums via
// sorted run-sum). Proven round-3/5 shape: 1024 threads = 16 waves; wave q
// owns graphs 4q..4q+3; thread (q, d2) owns dims {2d2, 2d2+1}. 2 blocks/CU.
// ---------------------------------------------------------------------------
__device__ __forceinline__ void pk_fma(float2& a, float s, float2 v)
{
    a.x = fmaf(s, v.x, a.x);
    a.y = fmaf(s, v.y, a.y);
}

#define FLUSH_X()                                                       \
    if ((cur_g >> 2) == q) {                                            \
        switch (cur_g & 3) {                                            \
            case 0: xA.x += rs.x; xA.y += rs.y; break;                  \
            case 1: xB.x += rs.x; xB.y += rs.y; break;                  \
            case 2: xC.x += rs.x; xC.y += rs.y; break;                  \
            case 3: xD.x += rs.x; xD.y += rs.y; break;                  \
        }                                                               \
    }

__global__ __launch_bounds__(1024) void gemm_kernel(
    const float* __restrict__ x, const uint* __restrict__ cnt,
    const int* __restrict__ batch,
    float* __restrict__ partA, float* __restrict__ partX, int NBe)
{
    __shared__ float xs[TILE * D];       // 32 KB
    __shared__ float cs[TILE * 68];      // padded rows (16B-aligned)
    __shared__ int   bs[TILE];

    const int t  = threadIdx.x;
    const int d2 = t & 63;
    const int q  = t >> 6;               // wave-uniform, 0..15

    float2 aA = {0,0}, aB = {0,0}, aC = {0,0}, aD = {0,0};
    float2 xA = {0,0}, xB = {0,0}, xC = {0,0}, xD = {0,0};
    float2 rs = {0,0};
    int cur_g = -1;

    const int ntiles = (N_NODES + TILE - 1) / TILE;
    for (int tb = blockIdx.x; tb < ntiles; tb += NBe) {
        const int base = tb * TILE;
        const int nvalid = min(TILE, N_NODES - base);

        #pragma unroll
        for (int k = 0; k < 2; ++k) {
            const int f4 = t + k * 1024;
            const int n  = f4 >> 5;
            const int c4 = f4 & 31;
            float4 v = make_float4(0.f, 0.f, 0.f, 0.f);
            if (n < nvalid)
                v = *reinterpret_cast<const float4*>(x + (size_t)(base + n) * D + c4 * 4);
            reinterpret_cast<float4*>(xs)[f4] = v;
        }
        {
            const int node = t >> 4, slot = t & 15;
            uint cv = 0u;
            if (node < nvalid) cv = cnt[(size_t)(base + node) * 16 + slot];
            float* cb = cs + node * 68 + slot * 4;
            cb[0] = (float)(cv & 255u);
            cb[1] = (float)((cv >> 8) & 255u);
            cb[2] = (float)((cv >> 16) & 255u);
            cb[3] = (float)(cv >> 24);
        }
        if (t < TILE) bs[t] = (t < nvalid) ? batch[base + t] : -1;
        __syncthreads();

        const float2* __restrict__ xv = reinterpret_cast<const float2*>(xs) + d2;
        const float*  __restrict__ cv = cs + q * 4;

        if (bs[0] == bs[TILE - 1]) {
            const int bg = bs[0];
            if (bg != cur_g) {
                FLUSH_X();
                rs.x = 0.f; rs.y = 0.f;
                cur_g = bg;
            }
            #pragma unroll 4
            for (int n = 0; n < TILE; ++n) {
                const float2 v = xv[n * 64];
                const float4 c = *reinterpret_cast<const float4*>(cv + n * 68);
                rs.x += v.x; rs.y += v.y;
                pk_fma(aA, c.x, v);
                pk_fma(aB, c.y, v);
                pk_fma(aC, c.z, v);
                pk_fma(aD, c.w, v);
            }
        } else {
            #pragma unroll 4
            for (int n = 0; n < TILE; ++n) {
                const float2 v = xv[n * 64];
                const float4 c = *reinterpret_cast<const float4*>(cv + n * 68);
                const int bg = bs[n];
                if (bg != cur_g) {                   // wave-uniform branch
                    FLUSH_X();
                    rs.x = 0.f; rs.y = 0.f;
                    cur_g = bg;
                }
                rs.x += v.x; rs.y += v.y;
                pk_fma(aA, c.x, v);
                pk_fma(aB, c.y, v);
                pk_fma(aC, c.z, v);
                pk_fma(aD, c.w, v);
            }
        }
        __syncthreads();
    }
    FLUSH_X();                                       // final run flush

    float* pa = partA + (size_t)blockIdx.x * (NG * D);
    float* px = partX + (size_t)blockIdx.x * (NG * D);
    const int gb = q * 4;
    reinterpret_cast<float2*>(pa + (size_t)(gb + 0) * D)[d2] = aA;
    reinterpret_cast<float2*>(pa + (size_t)(gb + 1) * D)[d2] = aB;
    reinterpret_cast<float2*>(pa + (size_t)(gb + 2) * D)[d2] = aC;
    reinterpret_cast<float2*>(pa + (size_t)(gb + 3) * D)[d2] = aD;
    reinterpret_cast<float2*>(px + (size_t)(gb + 0) * D)[d2] = xA;
    reinterpret_cast<float2*>(px + (size_t)(gb + 1) * D)[d2] = xB;
    reinterpret_cast<float2*>(px + (size_t)(gb + 2) * D)[d2] = xC;
    reinterpret_cast<float2*>(px + (size_t)(gb + 3) * D)[d2] = xD;
}

// ---------------------------------------------------------------------------
// Kernel 4: partial reduction, fully coalesced (256 blocks).
// ---------------------------------------------------------------------------
__global__ __launch_bounds__(256) void reduce1_kernel(
    const float* __restrict__ partA, const float* __restrict__ partX,
    float* __restrict__ tmp2, int NBe)
{
    const int cb = blockIdx.x & 63;
    const int pc = blockIdx.x >> 6;
    const int c  = cb * 256 + threadIdx.x;       // 0..16383
    const float* __restrict__ srcp =
        (c < NG * D) ? (partA + c) : (partX + (c - NG * D));
    const int chunk = (NBe + 3) >> 2;
    const int p0 = pc * chunk;
    int p1 = p0 + chunk; if (p1 > NBe) p1 = NBe;
    float s = 0.f;
    #pragma unroll 8
    for (int p = p0; p < p1; ++p) s += srcp[(size_t)p * (NG * D)];
    tmp2[pc * (2 * NG * D) + c] = s;
}

// ---------------------------------------------------------------------------
// Kernel 5: final 4-way sum + matvec pair + classifier. Block = graph.
// ---------------------------------------------------------------------------
__global__ __launch_bounds__(128) void final_kernel(
    const float* __restrict__ tmp2, const int* __restrict__ counts,
    const float* __restrict__ w_rel, const float* __restrict__ b_rel,
    const float* __restrict__ w_root,
    const float* __restrict__ w_lin, const float* __restrict__ b_lin,
    float* __restrict__ out)
{
    const int g = blockIdx.x;
    const int t = threadIdx.x;   // 0..127

    __shared__ float agg_s[D], x_s[D], p_s[D];
    float a = 0.f, xsum = 0.f;
    #pragma unroll
    for (int j = 0; j < 4; ++j) {
        a    += tmp2[j * (2 * NG * D) + g * D + t];
        xsum += tmp2[j * (2 * NG * D) + NG * D + g * D + t];
    }
    agg_s[t] = a; x_s[t] = xsum;
    __syncthreads();

    const float cn = (float)counts[g];
    float hj = b_rel[t] * cn;
    const float* __restrict__ wr = w_rel  + (size_t)t * D;
    const float* __restrict__ wo = w_root + (size_t)t * D;
    #pragma unroll 8
    for (int d0 = 0; d0 < D; ++d0) hj += agg_s[d0] * wr[d0] + x_s[d0] * wo[d0];
    p_s[t] = hj / fmaxf(cn, 1.f);
    __syncthreads();

    if (t < NC) {
        const float* __restrict__ wl = w_lin + (size_t)t * D;
        float o = b_lin[t];
        #pragma unroll 8
        for (int d0 = 0; d0 < D; ++d0) o += p_s[d0] * wl[d0];
        out[g * NC + t] = o;
    }
}

extern "C" void kernel_launch(void* const* d_in, const int* in_sizes, int n_in,
                              void* d_out, int out_size, void* d_ws, size_t ws_size,
                              hipStream_t stream)
{
    const float* x      = (const float*)d_in[0];
    const int*   ei     = (const int*)  d_in[1];
    const int*   batch  = (const int*)  d_in[2];
    const float* w_rel  = (const float*)d_in[3];
    const float* b_rel  = (const float*)d_in[4];
    const float* w_root = (const float*)d_in[5];
    const float* w_lin  = (const float*)d_in[6];
    const float* b_lin  = (const float*)d_in[7];
    float* out = (float*)d_out;

    // ws layout (u32 units):
    //   [tail NBUCK][counts 64][pad -> 512] [bdata NBUCK*BCAP/2] [cnt N*16]
    //   [partA NBe*8192 f] [partX NBe*8192 f] [tmp2 4*16384 f]
    uint*   tail   = (uint*)d_ws;
    int*    counts = (int*)(tail + NBUCK);
    ushort* bdata  = (ushort*)((uint*)d_ws + 512);
    const size_t bdata_u32 = (size_t)NBUCK * BCAP / 2;     // 1,601,536
    uint*   cnt    = (uint*)d_ws + 512 + bdata_u32;
    float*  partA  = (float*)(cnt + (size_t)N_NODES * 16);

    const size_t availf = ws_size / sizeof(float);
    const size_t headf  = 512 + bdata_u32 + (size_t)N_NODES * 16;
    const size_t tmp2f  = 4 * (size_t)(2 * NG * D);
    int NBe = NBMAX;
    if (headf + tmp2f + (size_t)NBe * 2 * NG * D > availf) {
        long long rem = (long long)availf - (long long)(headf + tmp2f);
        long long nb  = rem / (2 * NG * D);
        NBe = (nb < 1) ? 1 : (int)nb;
    }
    float* partX = partA + (size_t)NBe * NG * D;
    float* tmp2  = partX + (size_t)NBe * NG * D;

    const int fill_total = 512 + (int)bdata_u32;
    fill_kernel<<<2048, 256, 0, stream>>>((uint*)d_ws, 512, fill_total);
    bucket_kernel<<<ABLK + CBLK2, 1024, 0, stream>>>(ei, batch, tail, counts, bdata);
    hist_kernel<<<NBUCK, 256, 0, stream>>>(tail, bdata, cnt);
    gemm_kernel<<<NBe, 1024, 0, stream>>>(x, cnt, batch, partA, partX, NBe);
    reduce1_kernel<<<256, 256, 0, stream>>>(partA, partX, tmp2, NBe);
    final_kernel<<<NG, 128, 0, stream>>>(tmp2, counts,
                                         w_rel, b_rel, w_root, w_lin, b_lin, out);
}

// Round 8
// 113.538 us; speedup vs baseline: 1.3272x; 1.0022x over previous
//
#include <hip/hip_runtime.h>

#define N_NODES  100000
#define N_EDGES  1600000
#define D        128
#define NG       64
#define NC       10
#define NBMAX    512      // gemm grid: 2 blocks/CU (1024 thr each)
#define TILE     64       // nodes per LDS tile
#define EPT      8        // edges per thread in bucket_kernel
#define ABLK     196      // ceil(N_EDGES / (1024*EPT))
#define NBUCK    391      // ceil(N_NODES / 256) src buckets
#define BCAP     8192     // u16 slots per bucket (empirically sufficient, r6/r7)
#define CBLK2    98       // ceil(N_NODES / 1024) node-count blocks

typedef unsigned int uint;
typedef unsigned short ushort;
typedef unsigned long long ull;

// ws layout (u32 units)
#define OFF_COUNTS 391
#define OFF_AGGX   512                    // 8192 floats (self-sum accumulator)
#define ZERO_U32   8704                   // [tail|counts|aggX|pad) zeroed
#define BDATA_U32  (NBUCK * (BCAP / 2))   // 1,601,536
#define OFF_CNT    (ZERO_U32 + BDATA_U32)

static_assert(ABLK * 1024 * EPT >= N_EDGES, "edge coverage");
static_assert(NBUCK * 256 >= N_NODES, "bucket coverage");

// ---------------------------------------------------------------------------
// Kernel 0: zero tail/counts/aggX (35 KB). bdata sentinel-padding is now
// written by bucket_kernel itself (saves 6.4 MB of fill traffic).
// ---------------------------------------------------------------------------
__global__ __launch_bounds__(256) void fill_kernel(uint* __restrict__ p)
{
    const int i = blockIdx.x * 256 + threadIdx.x;
    if (i < ZERO_U32) p[i] = 0u;
}

// ---------------------------------------------------------------------------
// Kernel 1: edge bucketing. Blocks [0,ABLK): LDS-histogram 391 src-buckets,
// reserve 64B-aligned runs with ONE global atomic per touched bucket, scatter
// u16 records (src&255)<<6|g via LDS cursors, then write sentinel pads into
// own run gaps. Blocks [ABLK,ABLK+CBLK2): per-graph node counts (sorted-run).
// ---------------------------------------------------------------------------
__global__ __launch_bounds__(1024) void bucket_kernel(
    const int* __restrict__ ei, const int* __restrict__ batch,
    uint* __restrict__ tail, int* __restrict__ counts,
    ushort* __restrict__ bdata)
{
    const int b = blockIdx.x;
    if (b < ABLK) {
        __shared__ uint hs[NBUCK];
        __shared__ uint he[NBUCK];
        const int t = threadIdx.x;
        for (int i = t; i < NBUCK; i += 1024) hs[i] = 0u;
        __syncthreads();

        const int e0 = b * (1024 * EPT) + t * EPT;
        uint er[EPT];
        int  s[EPT], dn[EPT];
        bool v[EPT];
        if (e0 + EPT <= N_EDGES) {
            const int4 a0 = *reinterpret_cast<const int4*>(ei + e0);
            const int4 a1 = *reinterpret_cast<const int4*>(ei + e0 + 4);
            const int4 b0 = *reinterpret_cast<const int4*>(ei + N_EDGES + e0);
            const int4 b1 = *reinterpret_cast<const int4*>(ei + N_EDGES + e0 + 4);
            s[0]=a0.x; s[1]=a0.y; s[2]=a0.z; s[3]=a0.w;
            s[4]=a1.x; s[5]=a1.y; s[6]=a1.z; s[7]=a1.w;
            dn[0]=b0.x; dn[1]=b0.y; dn[2]=b0.z; dn[3]=b0.w;
            dn[4]=b1.x; dn[5]=b1.y; dn[6]=b1.z; dn[7]=b1.w;
            #pragma unroll
            for (int i = 0; i < EPT; ++i) v[i] = true;
        } else {
            #pragma unroll
            for (int i = 0; i < EPT; ++i) {
                v[i] = (e0 + i) < N_EDGES;
                s[i]  = v[i] ? ei[e0 + i] : 0;
                dn[i] = v[i] ? ei[N_EDGES + e0 + i] : 0;
            }
        }
        #pragma unroll
        for (int i = 0; i < EPT; ++i) {
            if (v[i]) {
                const uint g = (uint)batch[dn[i]];
                const uint k = (uint)s[i] >> 8;
                er[i] = (k << 16) | (((uint)s[i] & 255u) << 6) | g;
                atomicAdd(&hs[k], 1u);
            } else er[i] = 0xFFFFFFFFu;
        }
        __syncthreads();
        if (t < NBUCK) {
            const uint c = hs[t];
            uint r = 0u, a = 0u;
            if (c) { a = (c + 31u) & ~31u; r = atomicAdd(&tail[t], a); }
            hs[t] = r;
            he[t] = r + a;
        }
        __syncthreads();
        #pragma unroll
        for (int i = 0; i < EPT; ++i) {
            if (er[i] != 0xFFFFFFFFu) {
                const uint k = er[i] >> 16;
                const uint pos = atomicAdd(&hs[k], 1u);
                if (pos < BCAP)
                    bdata[(size_t)k * BCAP + pos] = (ushort)(er[i] & 0xFFFFu);
            }
        }
        __syncthreads();
        if (t < NBUCK) {
            uint p = hs[t];                  // cursor end = r + c
            uint e = he[t];
            if (e > BCAP) e = BCAP;
            for (; p < e; ++p) bdata[(size_t)t * BCAP + p] = 0xFFFFu;
        }
    } else {
        const int n = (b - ABLK) * 1024 + threadIdx.x;
        if (n >= N_NODES) return;
        const int lane = threadIdx.x & 63;
        const int g = batch[n];
        const bool lead = (n == 0) || (lane == 0) || (batch[n - 1] != g);
        const ull bl = __ballot(lead);
        if (lead) {
            const ull higher = (lane == 63) ? 0ull : (bl >> (lane + 1));
            int end = higher ? (lane + 1 + (__ffsll(higher) - 1)) : 64;
            const int wb = n - lane;
            int nv = N_NODES - wb; if (nv > 64) nv = 64;
            if (end > nv) end = nv;
            atomicAdd(&counts[g], end - lane);
        }
    }
}

// ---------------------------------------------------------------------------
// Kernel 2: per-bucket histogram -> packed-u8 cnt tile (coalesced writes).
// ---------------------------------------------------------------------------
__global__ __launch_bounds__(256) void hist_kernel(
    const uint* __restrict__ tail, const ushort* __restrict__ bdata,
    uint* __restrict__ cnt)
{
    __shared__ uint h2[256 * NG];          // 64 KB
    const int k = blockIdx.x;
    const int t = threadIdx.x;
    {
        const uint4 z = {0u, 0u, 0u, 0u};
        uint4* h4 = reinterpret_cast<uint4*>(h2);
        for (int i = t; i < 256 * NG / 4; i += 256) h4[i] = z;
    }
    __syncthreads();

    uint n = tail[k]; if (n > BCAP) n = BCAP;
    const ushort* __restrict__ bp = bdata + (size_t)k * BCAP;
    for (uint i = t; i < n; i += 256) {
        const uint r = bp[i];
        if (r != 0xFFFFu) atomicAdd(&h2[r], 1u);
    }
    __syncthreads();

    const int node0 = k * 256;
    const int nrows = min(256, N_NODES - node0);
    for (int j = t; j < nrows * 16; j += 256) {
        const int node = j >> 4, g4 = j & 15;
        const uint* hp = &h2[node * NG + g4 * 4];
        const uint w = (hp[0] & 255u) | ((hp[1] & 255u) << 8)
                     | ((hp[2] & 255u) << 16) | ((hp[3] & 255u) << 24);
        cnt[(size_t)(node0 + node) * 16 + g4] = w;
    }
}

// ---------------------------------------------------------------------------
// Kernel 3: dense GEMM  agg[g][d] = sum_n cnt[n][g]*x[n][d].
// 16 waves; wave q: graph-octet qq=q&7, node-half nh=q>>3 (nodes 32nh..+31).
// Lane l: half h=l>>5 -> graph quad gq=8qq+4h, dims dd=4(l&31). 16 MACs per
// (b128 x-read + b128 broadcast cnt-read) -> 1.5x better LDS cyc/MAC than r7.
// Self-sums: per-lane run accumulator rs (batch sorted); flushed at graph
// boundaries straight to global aggX via native f32 atomics (rare: ~300K).
// Node-halves combined in LDS (xs reuse) -> single partA partial per block.
// ---------------------------------------------------------------------------
__global__ __launch_bounds__(1024) void gemm_kernel(
    const float* __restrict__ x, const uint* __restrict__ cnt,
    const int* __restrict__ batch,
    float* __restrict__ partA, float* __restrict__ aggX, int NBe)
{
    __shared__ float xs[TILE * D];       // 32 KB (reused for half-combine)
    __shared__ float cs[TILE * 68];      // padded rows (16B-aligned)
    __shared__ int   bs[TILE];

    const int t  = threadIdx.x;
    const int l  = t & 63;
    const int q  = t >> 6;               // 0..15
    const int qq = q & 7;                // graph octet
    const int nh = q >> 3;               // node half
    const int h  = l >> 5;               // lane half
    const int gq = qq * 8 + h * 4;       // first graph of this thread's quad
    const int dd = (l & 31) * 4;         // first dim
    const int own = gq >> 2;             // run-flush ownership tag

    float4 a0 = {0,0,0,0}, a1 = {0,0,0,0}, a2 = {0,0,0,0}, a3 = {0,0,0,0};
    float4 rs = {0,0,0,0};
    int cur_g = -1;

    const int n0 = nh * 32, n1 = n0 + 32;
    const int ntiles = (N_NODES + TILE - 1) / TILE;

    for (int tb = blockIdx.x; tb < ntiles; tb += NBe) {
        const int base = tb * TILE;
        const int nvalid = min(TILE, N_NODES - base);

        #pragma unroll
        for (int k = 0; k < 2; ++k) {
            const int f4 = t + k * 1024;
            const int n  = f4 >> 5;
            const int c4 = f4 & 31;
            float4 v = make_float4(0.f, 0.f, 0.f, 0.f);
            if (n < nvalid)
                v = *reinterpret_cast<const float4*>(x + (size_t)(base + n) * D + c4 * 4);
            reinterpret_cast<float4*>(xs)[f4] = v;
        }
        {
            const int node = t >> 4, slot = t & 15;
            uint cv = 0u;
            if (node < nvalid) cv = cnt[(size_t)(base + node) * 16 + slot];
            float* cb = cs + node * 68 + slot * 4;
            cb[0] = (float)(cv & 255u);
            cb[1] = (float)((cv >> 8) & 255u);
            cb[2] = (float)((cv >> 16) & 255u);
            cb[3] = (float)(cv >> 24);
        }
        if (t < TILE) bs[t] = (t < nvalid) ? batch[base + t] : -1;
        __syncthreads();

        #pragma unroll 4
        for (int n = n0; n < n1; ++n) {
            const int bg = bs[n];
            const float4 v = *reinterpret_cast<const float4*>(xs + n * D + dd);
            const float4 c = *reinterpret_cast<const float4*>(cs + n * 68 + gq);
            if (bg != cur_g) {                       // uniform per half-wave
                if ((cur_g >> 2) == own) {
                    float* p = aggX + (size_t)cur_g * D + dd;
                    unsafeAtomicAdd(p + 0, rs.x);
                    unsafeAtomicAdd(p + 1, rs.y);
                    unsafeAtomicAdd(p + 2, rs.z);
                    unsafeAtomicAdd(p + 3, rs.w);
                }
                rs.x = 0.f; rs.y = 0.f; rs.z = 0.f; rs.w = 0.f;
                cur_g = bg;
            }
            rs.x += v.x; rs.y += v.y; rs.z += v.z; rs.w += v.w;
            a0.x = fmaf(c.x, v.x, a0.x); a0.y = fmaf(c.x, v.y, a0.y);
            a0.z = fmaf(c.x, v.z, a0.z); a0.w = fmaf(c.x, v.w, a0.w);
            a1.x = fmaf(c.y, v.x, a1.x); a1.y = fmaf(c.y, v.y, a1.y);
            a1.z = fmaf(c.y, v.z, a1.z); a1.w = fmaf(c.y, v.w, a1.w);
            a2.x = fmaf(c.z, v.x, a2.x); a2.y = fmaf(c.z, v.y, a2.y);
            a2.z = fmaf(c.z, v.z, a2.z); a2.w = fmaf(c.z, v.w, a2.w);
            a3.x = fmaf(c.w, v.x, a3.x); a3.y = fmaf(c.w, v.y, a3.y);
            a3.z = fmaf(c.w, v.z, a3.z); a3.w = fmaf(c.w, v.w, a3.w);
        }
        __syncthreads();
    }

    // final run flush
    if ((cur_g >> 2) == own) {
        float* p = aggX + (size_t)cur_g * D + dd;
        unsafeAtomicAdd(p + 0, rs.x);
        unsafeAtomicAdd(p + 1, rs.y);
        unsafeAtomicAdd(p + 2, rs.z);
        unsafeAtomicAdd(p + 3, rs.w);
    }

    // combine node-halves via xs (exactly NG*D floats), write single partial
    if (nh == 1) {
        *reinterpret_cast<float4*>(xs + (gq + 0) * D + dd) = a0;
        *reinterpret_cast<float4*>(xs + (gq + 1) * D + dd) = a1;
        *reinterpret_cast<float4*>(xs + (gq + 2) * D + dd) = a2;
        *reinterpret_cast<float4*>(xs + (gq + 3) * D + dd) = a3;
    }
    __syncthreads();
    if (nh == 0) {
        float* pa = partA + (size_t)blockIdx.x * (NG * D);
        const float4 b0 = *reinterpret_cast<const float4*>(xs + (gq + 0) * D + dd);
        const float4 b1 = *reinterpret_cast<const float4*>(xs + (gq + 1) * D + dd);
        const float4 b2 = *reinterpret_cast<const float4*>(xs + (gq + 2) * D + dd);
        const float4 b3 = *reinterpret_cast<const float4*>(xs + (gq + 3) * D + dd);
        a0.x += b0.x; a0.y += b0.y; a0.z += b0.z; a0.w += b0.w;
        a1.x += b1.x; a1.y += b1.y; a1.z += b1.z; a1.w += b1.w;
        a2.x += b2.x; a2.y += b2.y; a2.z += b2.z; a2.w += b2.w;
        a3.x += b3.x; a3.y += b3.y; a3.z += b3.z; a3.w += b3.w;
        *reinterpret_cast<float4*>(pa + (size_t)(gq + 0) * D + dd) = a0;
        *reinterpret_cast<float4*>(pa + (size_t)(gq + 1) * D + dd) = a1;
        *reinterpret_cast<float4*>(pa + (size_t)(gq + 2) * D + dd) = a2;
        *reinterpret_cast<float4*>(pa + (size_t)(gq + 3) * D + dd) = a3;
    }
}

// ---------------------------------------------------------------------------
// Kernel 4: partial reduction (partA only now). 128 blocks = 32 column-blocks
// x 4 partial-chunks. Writes tmp2[pc][8192].
// ---------------------------------------------------------------------------
__global__ __launch_bounds__(256) void reduce1_kernel(
    const float* __restrict__ partA, float* __restrict__ tmp2, int NBe)
{
    const int cb = blockIdx.x & 31;
    const int pc = blockIdx.x >> 5;
    const int c  = cb * 256 + threadIdx.x;       // 0..8191
    const int chunk = (NBe + 3) >> 2;
    const int p0 = pc * chunk;
    int p1 = p0 + chunk; if (p1 > NBe) p1 = NBe;
    float s = 0.f;
    #pragma unroll 8
    for (int p = p0; p < p1; ++p) s += partA[(size_t)p * (NG * D) + c];
    tmp2[pc * (NG * D) + c] = s;
}

// ---------------------------------------------------------------------------
// Kernel 5: final 4-way sum + matvec pair + classifier. Block = graph.
// ---------------------------------------------------------------------------
__global__ __launch_bounds__(128) void final_kernel(
    const float* __restrict__ tmp2, const float* __restrict__ aggX,
    const int* __restrict__ counts,
    const float* __restrict__ w_rel, const float* __restrict__ b_rel,
    const float* __restrict__ w_root,
    const float* __restrict__ w_lin, const float* __restrict__ b_lin,
    float* __restrict__ out)
{
    const int g = blockIdx.x;
    const int t = threadIdx.x;   // 0..127

    __shared__ float agg_s[D], x_s[D], p_s[D];
    float a = 0.f;
    #pragma unroll
    for (int j = 0; j < 4; ++j) a += tmp2[j * (NG * D) + g * D + t];
    agg_s[t] = a;
    x_s[t]   = aggX[(size_t)g * D + t];
    __syncthreads();

    const float cn = (float)counts[g];
    float hj = b_rel[t] * cn;
    const float* __restrict__ wr = w_rel  + (size_t)t * D;
    const float* __restrict__ wo = w_root + (size_t)t * D;
    #pragma unroll 8
    for (int d0 = 0; d0 < D; ++d0) hj += agg_s[d0] * wr[d0] + x_s[d0] * wo[d0];
    p_s[t] = hj / fmaxf(cn, 1.f);
    __syncthreads();

    if (t < NC) {
        const float* __restrict__ wl = w_lin + (size_t)t * D;
        float o = b_lin[t];
        #pragma unroll 8
        for (int d0 = 0; d0 < D; ++d0) o += p_s[d0] * wl[d0];
        out[g * NC + t] = o;
    }
}

extern "C" void kernel_launch(void* const* d_in, const int* in_sizes, int n_in,
                              void* d_out, int out_size, void* d_ws, size_t ws_size,
                              hipStream_t stream)
{
    const float* x      = (const float*)d_in[0];
    const int*   ei     = (const int*)  d_in[1];
    const int*   batch  = (const int*)  d_in[2];
    const float* w_rel  = (const float*)d_in[3];
    const float* b_rel  = (const float*)d_in[4];
    const float* w_root = (const float*)d_in[5];
    const float* w_lin  = (const float*)d_in[6];
    const float* b_lin  = (const float*)d_in[7];
    float* out = (float*)d_out;

    // ws layout (u32 units):
    //   [tail 391][counts 64][pad][aggX 8192 f @512][pad -> 8704]
    //   [bdata NBUCK*BCAP/2] [cnt N*16] [partA NBe*8192 f] [tmp2 4*8192 f]
    uint*   tail   = (uint*)d_ws;
    int*    counts = (int*)(tail + OFF_COUNTS);
    float*  aggX   = (float*)(tail + OFF_AGGX);
    ushort* bdata  = (ushort*)(tail + ZERO_U32);
    uint*   cnt    = tail + OFF_CNT;
    float*  partA  = (float*)(cnt + (size_t)N_NODES * 16);

    const size_t availf = ws_size / sizeof(float);
    const size_t headf  = OFF_CNT + (size_t)N_NODES * 16;
    const size_t tmp2f  = 4 * (size_t)(NG * D);
    int NBe = NBMAX;
    if (headf + tmp2f + (size_t)NBe * NG * D > availf) {
        long long rem = (long long)availf - (long long)(headf + tmp2f);
        long long nb  = rem / (NG * D);
        NBe = (nb < 1) ? 1 : (int)nb;
    }
    float* tmp2 = partA + (size_t)NBe * NG * D;

    fill_kernel<<<(ZERO_U32 + 255) / 256, 256, 0, stream>>>(tail);
    bucket_kernel<<<ABLK + CBLK2, 1024, 0, stream>>>(ei, batch, tail, counts, bdata);
    hist_kernel<<<NBUCK, 256, 0, stream>>>(tail, bdata, cnt);
    gemm_kernel<<<NBe, 1024, 0, stream>>>(x, cnt, batch, partA, aggX, NBe);
    reduce1_kernel<<<128, 256, 0, stream>>>(partA, tmp2, NBe);
    final_kernel<<<NG, 128, 0, stream>>>(tmp2, aggX, counts,
                                         w_rel, b_rel, w_root, w_lin, b_lin, out);
}

// Round 9
// 83.675 us; speedup vs baseline: 1.8008x; 1.3569x over previous
//
#include <hip/hip_runtime.h>

#define N_NODES  100000
#define N_EDGES  1600000
#define D        128
#define NG       64
#define NC       10
#define NBMAX    512      // gemm grid: 2 blocks/CU (1024 thr each)
#define TILE     64       // nodes per LDS tile
#define EPT      8        // edges per thread in bucket_kernel
#define ABLK     196      // ceil(N_EDGES / (1024*EPT))
#define NBUCK    391      // ceil(N_NODES / 256) src buckets
#define BCAP     8192     // u16 slots per bucket (empirically sufficient r6-r8)
#define CBLK2    98       // ceil(N_NODES / 1024) node-count blocks
#define CIW      68       // ci row stride (u32)
#define XSW      130      // xsp row stride (u32); 130 mod 4 = 2 -> b64 writes,
                          // 130 mod 32 = 2 -> 2-way banks on strided b32 reads

typedef unsigned int uint;
typedef unsigned short ushort;
typedef unsigned long long ull;
typedef short bhalf8 __attribute__((ext_vector_type(8)));
typedef float f32x4  __attribute__((ext_vector_type(4)));

#define MFMA_BF16 __builtin_amdgcn_mfma_f32_16x16x32_bf16

// ws layout (u32 units)
#define OFF_COUNTS 391
#define ZERO_U32   512                    // [tail|counts|pad) zeroed
#define BDATA_U32  (NBUCK * (BCAP / 2))   // 1,601,536
#define OFF_CNT    (ZERO_U32 + BDATA_U32)

static_assert(ABLK * 1024 * EPT >= N_EDGES, "edge coverage");
static_assert(NBUCK * 256 >= N_NODES, "bucket coverage");

// ---------------------------------------------------------------------------
// Kernel 0: zero tail + counts.
// ---------------------------------------------------------------------------
__global__ __launch_bounds__(256) void fill_kernel(uint* __restrict__ p)
{
    const int i = blockIdx.x * 256 + threadIdx.x;
    if (i < ZERO_U32) p[i] = 0u;
}

// ---------------------------------------------------------------------------
// Kernel 1: edge bucketing (proven r7/r8). Blocks [0,ABLK): LDS-histogram 391
// src-buckets, reserve 64B-aligned runs with ONE global atomic per touched
// bucket, scatter u16 records (src&255)<<6|g via LDS cursors, write sentinel
// pads into own gaps. Blocks [ABLK,+CBLK2): per-graph node counts.
// ---------------------------------------------------------------------------
__global__ __launch_bounds__(1024) void bucket_kernel(
    const int* __restrict__ ei, const int* __restrict__ batch,
    uint* __restrict__ tail, int* __restrict__ counts,
    ushort* __restrict__ bdata)
{
    const int b = blockIdx.x;
    if (b < ABLK) {
        __shared__ uint hs[NBUCK];
        __shared__ uint he[NBUCK];
        const int t = threadIdx.x;
        for (int i = t; i < NBUCK; i += 1024) hs[i] = 0u;
        __syncthreads();

        const int e0 = b * (1024 * EPT) + t * EPT;
        uint er[EPT];
        int  s[EPT], dn[EPT];
        bool v[EPT];
        if (e0 + EPT <= N_EDGES) {
            const int4 a0 = *reinterpret_cast<const int4*>(ei + e0);
            const int4 a1 = *reinterpret_cast<const int4*>(ei + e0 + 4);
            const int4 b0 = *reinterpret_cast<const int4*>(ei + N_EDGES + e0);
            const int4 b1 = *reinterpret_cast<const int4*>(ei + N_EDGES + e0 + 4);
            s[0]=a0.x; s[1]=a0.y; s[2]=a0.z; s[3]=a0.w;
            s[4]=a1.x; s[5]=a1.y; s[6]=a1.z; s[7]=a1.w;
            dn[0]=b0.x; dn[1]=b0.y; dn[2]=b0.z; dn[3]=b0.w;
            dn[4]=b1.x; dn[5]=b1.y; dn[6]=b1.z; dn[7]=b1.w;
            #pragma unroll
            for (int i = 0; i < EPT; ++i) v[i] = true;
        } else {
            #pragma unroll
            for (int i = 0; i < EPT; ++i) {
                v[i] = (e0 + i) < N_EDGES;
                s[i]  = v[i] ? ei[e0 + i] : 0;
                dn[i] = v[i] ? ei[N_EDGES + e0 + i] : 0;
            }
        }
        #pragma unroll
        for (int i = 0; i < EPT; ++i) {
            if (v[i]) {
                const uint g = (uint)batch[dn[i]];
                const uint k = (uint)s[i] >> 8;
                er[i] = (k << 16) | (((uint)s[i] & 255u) << 6) | g;
                atomicAdd(&hs[k], 1u);
            } else er[i] = 0xFFFFFFFFu;
        }
        __syncthreads();
        if (t < NBUCK) {
            const uint c = hs[t];
            uint r = 0u, a = 0u;
            if (c) { a = (c + 31u) & ~31u; r = atomicAdd(&tail[t], a); }
            hs[t] = r;
            he[t] = r + a;
        }
        __syncthreads();
        #pragma unroll
        for (int i = 0; i < EPT; ++i) {
            if (er[i] != 0xFFFFFFFFu) {
                const uint k = er[i] >> 16;
                const uint pos = atomicAdd(&hs[k], 1u);
                if (pos < BCAP)
                    bdata[(size_t)k * BCAP + pos] = (ushort)(er[i] & 0xFFFFu);
            }
        }
        __syncthreads();
        if (t < NBUCK) {
            uint p = hs[t];
            uint e = he[t];
            if (e > BCAP) e = BCAP;
            for (; p < e; ++p) bdata[(size_t)t * BCAP + p] = 0xFFFFu;
        }
    } else {
        const int n = (b - ABLK) * 1024 + threadIdx.x;
        if (n >= N_NODES) return;
        const int lane = threadIdx.x & 63;
        const int g = batch[n];
        const bool lead = (n == 0) || (lane == 0) || (batch[n - 1] != g);
        const ull bl = __ballot(lead);
        if (lead) {
            const ull higher = (lane == 63) ? 0ull : (bl >> (lane + 1));
            int end = higher ? (lane + 1 + (__ffsll(higher) - 1)) : 64;
            const int wb = n - lane;
            int nv = N_NODES - wb; if (nv > 64) nv = 64;
            if (end > nv) end = nv;
            atomicAdd(&counts[g], end - lane);
        }
    }
}

// ---------------------------------------------------------------------------
// Kernel 2: per-bucket histogram -> packed-u8 cnt tile (proven r7/r8).
// ---------------------------------------------------------------------------
__global__ __launch_bounds__(256) void hist_kernel(
    const uint* __restrict__ tail, const ushort* __restrict__ bdata,
    uint* __restrict__ cnt)
{
    __shared__ uint h2[256 * NG];          // 64 KB
    const int k = blockIdx.x;
    const int t = threadIdx.x;
    {
        const uint4 z = {0u, 0u, 0u, 0u};
        uint4* h4 = reinterpret_cast<uint4*>(h2);
        for (int i = t; i < 256 * NG / 4; i += 256) h4[i] = z;
    }
    __syncthreads();

    uint n = tail[k]; if (n > BCAP) n = BCAP;
    const ushort* __restrict__ bp = bdata + (size_t)k * BCAP;
    for (uint i = t; i < n; i += 256) {
        const uint r = bp[i];
        if (r != 0xFFFFu) atomicAdd(&h2[r], 1u);
    }
    __syncthreads();

    const int node0 = k * 256;
    const int nrows = min(256, N_NODES - node0);
    for (int j = t; j < nrows * 16; j += 256) {
        const int node = j >> 4, g4 = j & 15;
        const uint* hp = &h2[node * NG + g4 * 4];
        const uint w = (hp[0] & 255u) | ((hp[1] & 255u) << 8)
                     | ((hp[2] & 255u) << 16) | ((hp[3] & 255u) << 24);
        cnt[(size_t)(node0 + node) * 16 + g4] = w;
    }
}

// ---------------------------------------------------------------------------
// split-bf16 pack: u32 = bf16_rne(f) | bf16_rne(f - hi) << 16.
// cnt*hi and cnt*lo products are exact in the fp32 MFMA accumulator.
// ---------------------------------------------------------------------------
__device__ __forceinline__ uint packbf(float f)
{
    const uint u  = __float_as_uint(f);
    const uint hb = (u + 0x7FFFu + ((u >> 16) & 1u)) >> 16;
    const float hf = __uint_as_float(hb << 16);
    const uint ul = __float_as_uint(f - hf);
    const uint lb = (ul + 0x7FFFu + ((ul >> 16) & 1u)) >> 16;
    return hb | (lb << 16);
}

// ---------------------------------------------------------------------------
// Kernel 3: MFMA GEMM.  aggA = cnt . x   and   aggX = ind . x  (ind = one-hot
// of batch) in one pass, mfma_f32_16x16x32_bf16, x split hi+lo bf16.
// 16 waves; wave w: m-tile mt=w&3 (16 graphs), n-tiles nt0,nt0+1 (32 dims).
// Fragment layout: A[l&15][(l>>4)*8+i], B[(l>>4)*8+i][l&15],
//                  C row=(l>>4)*4+r, col=l&15  (guide Sec.3, m89-verified C).
// LDS: xsp[node][dim] u32 (hi|lo packed, stride 130: 2-way banks on the
// strided B reads); ci[graph][node] u32 (cnt bf16 | ind bf16<<16, stride 68).
// Per 32-K chunk per wave: 2 b128 + 16 b32 LDS + 16 MFMA  (~5x fewer LDS
// instrs than the VALU version). 50.7 KB LDS -> 2 blocks/CU.
// ---------------------------------------------------------------------------
__global__ __launch_bounds__(1024, 8) void gemm_kernel(
    const float* __restrict__ x, const uint* __restrict__ cnt,
    const int* __restrict__ batch,
    float* __restrict__ partA, float* __restrict__ partX, int NBe)
{
    __shared__ uint xsp[TILE * XSW];   // 33.3 KB
    __shared__ uint ci[NG * CIW];      // 17.4 KB

    const int t   = threadIdx.x;
    const int l   = t & 63;
    const int w   = t >> 6;
    const int mt  = w & 3;
    const int nt0 = (w >> 2) << 1;
    const int lr  = l & 15;
    const int lh  = l >> 4;

    f32x4 aA0 = {0,0,0,0}, aA1 = {0,0,0,0};
    f32x4 aX0 = {0,0,0,0}, aX1 = {0,0,0,0};

    const int ntiles = (N_NODES + TILE - 1) / TILE;
    for (int tb = blockIdx.x; tb < ntiles; tb += NBe) {
        const int base = tb * TILE;
        const int nvalid = min(TILE, N_NODES - base);

        // stage x -> xsp (coalesced f4 reads, b64 LDS writes)
        #pragma unroll
        for (int k = 0; k < 2; ++k) {
            const int f4i = t + k * 1024;
            const int n = f4i >> 5, c4 = f4i & 31;
            float4 v = make_float4(0.f, 0.f, 0.f, 0.f);
            if (n < nvalid)
                v = *reinterpret_cast<const float4*>(x + (size_t)(base + n) * D + c4 * 4);
            uint2 p01, p23;
            p01.x = packbf(v.x); p01.y = packbf(v.y);
            p23.x = packbf(v.z); p23.y = packbf(v.w);
            uint* dst = xsp + n * XSW + c4 * 4;
            *reinterpret_cast<uint2*>(dst)     = p01;
            *reinterpret_cast<uint2*>(dst + 2) = p23;
        }
        // stage cnt+ind -> ci
        {
            const int node = t >> 4, slot = t & 15;
            uint cv = 0u; int gb = -1;
            if (node < nvalid) {
                cv = cnt[(size_t)(base + node) * 16 + slot];
                gb = batch[base + node];
            }
            #pragma unroll
            for (int j = 0; j < 4; ++j) {
                const int g = slot * 4 + j;
                const uint c = (cv >> (8 * j)) & 255u;
                uint val = __float_as_uint((float)c) >> 16;   // exact bf16(cnt)
                if (gb == g) val |= 0x3F800000u;              // bf16(1.0) in hi16
                ci[g * CIW + node] = val;
            }
        }
        __syncthreads();

        #pragma unroll
        for (int kc = 0; kc < 2; ++kc) {
            const int k0 = kc * 32;
            const uint* cip = ci + (mt * 16 + lr) * CIW + k0 + lh * 8;
            const uint4 ca = *reinterpret_cast<const uint4*>(cip);
            const uint4 cb = *reinterpret_cast<const uint4*>(cip + 4);
            bhalf8 acnt, aind;
            acnt[0]=(short)ca.x; aind[0]=(short)(ca.x>>16);
            acnt[1]=(short)ca.y; aind[1]=(short)(ca.y>>16);
            acnt[2]=(short)ca.z; aind[2]=(short)(ca.z>>16);
            acnt[3]=(short)ca.w; aind[3]=(short)(ca.w>>16);
            acnt[4]=(short)cb.x; aind[4]=(short)(cb.x>>16);
            acnt[5]=(short)cb.y; aind[5]=(short)(cb.y>>16);
            acnt[6]=(short)cb.z; aind[6]=(short)(cb.z>>16);
            acnt[7]=(short)cb.w; aind[7]=(short)(cb.w>>16);

            const uint* xb = xsp + (k0 + lh * 8) * XSW + lr;
            {
                const uint* xp = xb + nt0 * 16;
                const uint r0=xp[0],      r1=xp[XSW],   r2=xp[2*XSW], r3=xp[3*XSW],
                           r4=xp[4*XSW],  r5=xp[5*XSW], r6=xp[6*XSW], r7=xp[7*XSW];
                bhalf8 bh, bl;
                bh[0]=(short)r0; bl[0]=(short)(r0>>16);
                bh[1]=(short)r1; bl[1]=(short)(r1>>16);
                bh[2]=(short)r2; bl[2]=(short)(r2>>16);
                bh[3]=(short)r3; bl[3]=(short)(r3>>16);
                bh[4]=(short)r4; bl[4]=(short)(r4>>16);
                bh[5]=(short)r5; bl[5]=(short)(r5>>16);
                bh[6]=(short)r6; bl[6]=(short)(r6>>16);
                bh[7]=(short)r7; bl[7]=(short)(r7>>16);
                aA0 = MFMA_BF16(acnt, bh, aA0, 0, 0, 0);
                aA0 = MFMA_BF16(acnt, bl, aA0, 0, 0, 0);
                aX0 = MFMA_BF16(aind, bh, aX0, 0, 0, 0);
                aX0 = MFMA_BF16(aind, bl, aX0, 0, 0, 0);
            }
            {
                const uint* xp = xb + (nt0 + 1) * 16;
                const uint r0=xp[0],      r1=xp[XSW],   r2=xp[2*XSW], r3=xp[3*XSW],
                           r4=xp[4*XSW],  r5=xp[5*XSW], r6=xp[6*XSW], r7=xp[7*XSW];
                bhalf8 bh, bl;
                bh[0]=(short)r0; bl[0]=(short)(r0>>16);
                bh[1]=(short)r1; bl[1]=(short)(r1>>16);
                bh[2]=(short)r2; bl[2]=(short)(r2>>16);
                bh[3]=(short)r3; bl[3]=(short)(r3>>16);
                bh[4]=(short)r4; bl[4]=(short)(r4>>16);
                bh[5]=(short)r5; bl[5]=(short)(r5>>16);
                bh[6]=(short)r6; bl[6]=(short)(r6>>16);
                bh[7]=(short)r7; bl[7]=(short)(r7>>16);
                aA1 = MFMA_BF16(acnt, bh, aA1, 0, 0, 0);
                aA1 = MFMA_BF16(acnt, bl, aA1, 0, 0, 0);
                aX1 = MFMA_BF16(aind, bh, aX1, 0, 0, 0);
                aX1 = MFMA_BF16(aind, bl, aX1, 0, 0, 0);
            }
        }
        __syncthreads();
    }

    // epilogue: C row=(l>>4)*4+r, col=l&15
    float* pa = partA + (size_t)blockIdx.x * (NG * D);
    float* px = partX + (size_t)blockIdx.x * (NG * D);
    #pragma unroll
    for (int r = 0; r < 4; ++r) {
        const int row = mt * 16 + lh * 4 + r;
        pa[row * D + nt0 * 16 + lr]       = aA0[r];
        pa[row * D + (nt0 + 1) * 16 + lr] = aA1[r];
        px[row * D + nt0 * 16 + lr]       = aX0[r];
        px[row * D + (nt0 + 1) * 16 + lr] = aX1[r];
    }
}

// ---------------------------------------------------------------------------
// Kernel 4: partial reduction, fully coalesced (256 blocks over [A|X]).
// ---------------------------------------------------------------------------
__global__ __launch_bounds__(256) void reduce1_kernel(
    const float* __restrict__ partA, const float* __restrict__ partX,
    float* __restrict__ tmp2, int NBe)
{
    const int cb = blockIdx.x & 63;
    const int pc = blockIdx.x >> 6;
    const int c  = cb * 256 + threadIdx.x;       // 0..16383
    const float* __restrict__ srcp =
        (c < NG * D) ? (partA + c) : (partX + (c - NG * D));
    const int chunk = (NBe + 3) >> 2;
    const int p0 = pc * chunk;
    int p1 = p0 + chunk; if (p1 > NBe) p1 = NBe;
    float s = 0.f;
    #pragma unroll 8
    for (int p = p0; p < p1; ++p) s += srcp[(size_t)p * (NG * D)];
    tmp2[pc * (2 * NG * D) + c] = s;
}

// ---------------------------------------------------------------------------
// Kernel 5: final 4-way sum + matvec pair + classifier. Block = graph.
// ---------------------------------------------------------------------------
__global__ __launch_bounds__(128) void final_kernel(
    const float* __restrict__ tmp2, const int* __restrict__ counts,
    const float* __restrict__ w_rel, const float* __restrict__ b_rel,
    const float* __restrict__ w_root,
    const float* __restrict__ w_lin, const float* __restrict__ b_lin,
    float* __restrict__ out)
{
    const int g = blockIdx.x;
    const int t = threadIdx.x;   // 0..127

    __shared__ float agg_s[D], x_s[D], p_s[D];
    float a = 0.f, xsum = 0.f;
    #pragma unroll
    for (int j = 0; j < 4; ++j) {
        a    += tmp2[j * (2 * NG * D) + g * D + t];
        xsum += tmp2[j * (2 * NG * D) + NG * D + g * D + t];
    }
    agg_s[t] = a; x_s[t] = xsum;
    __syncthreads();

    const float cn = (float)counts[g];
    float hj = b_rel[t] * cn;
    const float* __restrict__ wr = w_rel  + (size_t)t * D;
    const float* __restrict__ wo = w_root + (size_t)t * D;
    #pragma unroll 8
    for (int d0 = 0; d0 < D; ++d0) hj += agg_s[d0] * wr[d0] + x_s[d0] * wo[d0];
    p_s[t] = hj / fmaxf(cn, 1.f);
    __syncthreads();

    if (t < NC) {
        const float* __restrict__ wl = w_lin + (size_t)t * D;
        float o = b_lin[t];
        #pragma unroll 8
        for (int d0 = 0; d0 < D; ++d0) o += p_s[d0] * wl[d0];
        out[g * NC + t] = o;
    }
}

extern "C" void kernel_launch(void* const* d_in, const int* in_sizes, int n_in,
                              void* d_out, int out_size, void* d_ws, size_t ws_size,
                              hipStream_t stream)
{
    const float* x      = (const float*)d_in[0];
    const int*   ei     = (const int*)  d_in[1];
    const int*   batch  = (const int*)  d_in[2];
    const float* w_rel  = (const float*)d_in[3];
    const float* b_rel  = (const float*)d_in[4];
    const float* w_root = (const float*)d_in[5];
    const float* w_lin  = (const float*)d_in[6];
    const float* b_lin  = (const float*)d_in[7];
    float* out = (float*)d_out;

    // ws layout (u32 units):
    //   [tail 391][counts 64][pad -> 512] [bdata NBUCK*BCAP/2] [cnt N*16]
    //   [partA NBe*8192 f] [partX NBe*8192 f] [tmp2 4*16384 f]
    uint*   tail   = (uint*)d_ws;
    int*    counts = (int*)(tail + OFF_COUNTS);
    ushort* bdata  = (ushort*)(tail + ZERO_U32);
    uint*   cnt    = tail + OFF_CNT;
    float*  partA  = (float*)(cnt + (size_t)N_NODES * 16);

    const size_t availf = ws_size / sizeof(float);
    const size_t headf  = OFF_CNT + (size_t)N_NODES * 16;
    const size_t tmp2f  = 4 * (size_t)(2 * NG * D);
    int NBe = NBMAX;
    if (headf + tmp2f + (size_t)NBe * 2 * NG * D > availf) {
        long long rem = (long long)availf - (long long)(headf + tmp2f);
        long long nb  = rem / (2 * NG * D);
        NBe = (nb < 1) ? 1 : (int)nb;
    }
    float* partX = partA + (size_t)NBe * NG * D;
    float* tmp2  = partX + (size_t)NBe * NG * D;

    fill_kernel<<<2, 256, 0, stream>>>(tail);
    bucket_kernel<<<ABLK + CBLK2, 1024, 0, stream>>>(ei, batch, tail, counts, bdata);
    hist_kernel<<<NBUCK, 256, 0, stream>>>(tail, bdata, cnt);
    gemm_kernel<<<NBe, 1024, 0, stream>>>(x, cnt, batch, partA, partX, NBe);
    reduce1_kernel<<<256, 256, 0, stream>>>(partA, partX, tmp2, NBe);
    final_kernel<<<NG, 128, 0, stream>>>(tmp2, counts,
                                         w_rel, b_rel, w_root, w_lin, b_lin, out);
}